// Round 11
// baseline (1577.489 us; speedup 1.0000x reference)
//
#include <hip/hip_runtime.h>
#include <cstdint>
#include <cstddef>

typedef __attribute__((ext_vector_type(4))) float fvec4;
typedef __attribute__((ext_vector_type(8))) short bf8;            // 8 bf16 = 4 VGPR MFMA frag
typedef __attribute__((ext_vector_type(8))) unsigned short usvec8;
typedef __attribute__((ext_vector_type(4))) float f32x4;

#define NNODES 100000
#define NEDGES 1600000
#define INDIM  128
#define HC     128
#define NH     8
#define LEAKY  0.2f
#define SM_EPS 1e-16f
#define BM     64    // nodes per block in k_gemm
#define GEMM_BLOCKS ((NNODES + BM - 1) / BM)   // 1563
#define WROWS  272   // 256 W cols + 8 wa_l + 8 wa_r
#define NPB_M  128   // dst nodes per aggregation bucket
#define NBUCK  ((NNODES + NPB_M - 1) / NPB_M)  // 782
#define CHUNK  1024  // edges per gemm block for bucket counting
#define CBLK   GEMM_BLOCKS                     // 1563; 1563*1024 >= 1.6M

__device__ __forceinline__ unsigned short f2bf_rne(float f) {
    uint32_t u = __builtin_bit_cast(uint32_t, f);
    u += 0x7FFFu + ((u >> 16) & 1u);
    return (unsigned short)(u >> 16);
}
__device__ __forceinline__ float bf2f(uint32_t lo16) {
    return __builtin_bit_cast(float, lo16 << 16);
}

// ---------------------------------------------------------------------------
// k_wt: build wt_g (bf16):
//   rows 0..255:  W_lin|W_res transposed [n][k], pre-swizzled 16B slots (^= n&7)
//   rows 256..263: wa_l[k,hd]; rows 264..271: wa_r (att folded into W_lin).
// ---------------------------------------------------------------------------
__global__ __launch_bounds__(256) void k_wt(
    const float* __restrict__ W_lin,
    const float* __restrict__ W_res,
    const float* __restrict__ att_l,
    const float* __restrict__ att_r,
    unsigned short* __restrict__ wt_g)
{
    const int idx = blockIdx.x * 256 + threadIdx.x;   // 0..4351
    if (idx >= WROWS * 16) return;
    const int n  = idx >> 4;                          // 0..271
    const int k8 = idx & 15;
    usvec8 o;
    if (n < 256) {
        const float* src = (n < 128) ? W_lin : W_res;
        const int col = n & 127;
        #pragma unroll
        for (int j = 0; j < 8; ++j)
            o[j] = f2bf_rne(src[(size_t)(k8 * 8 + j) * HC + col]);
        const int sw = k8 ^ (n & 7);
        *(usvec8*)&wt_g[(size_t)n * INDIM + sw * 8] = o;
    } else {
        const int hd = (n - 256) & 7;
        const float* att = (n < 264) ? att_l : att_r;
        #pragma unroll
        for (int j = 0; j < 8; ++j) {
            const int k = k8 * 8 + j;
            float s = 0.f;
            #pragma unroll
            for (int c = 0; c < 16; ++c)
                s += W_lin[(size_t)k * HC + 16 * hd + c] * att[16 * hd + c];
            o[j] = f2bf_rne(s);
        }
        *(usvec8*)&wt_g[(size_t)n * INDIM + k8 * 8] = o;
    }
}

// ---------------------------------------------------------------------------
// k_gemm (MFMA): per block 64 nodes x 272 cols (h | resid | alphas), K=128.
// LDS: wt 64KB + xs 16KB = 80KB -> 2 blocks/CU.
// Fused per-(chunk,bucket) edge counting via reused wt LDS (before staging).
// ---------------------------------------------------------------------------
__global__ __launch_bounds__(256) void k_gemm(
    const float* __restrict__ x,
    const unsigned short* __restrict__ wt_g,
    const int*   __restrict__ ei,
    unsigned short* __restrict__ h16,
    unsigned short* __restrict__ resid16,
    float* __restrict__ alpha_l,
    float* __restrict__ alpha_r,
    int* __restrict__ cnt)
{
    __shared__ unsigned short wt[256 * INDIM];  // 64 KB
    __shared__ unsigned short xs[BM * INDIM];   // 16 KB

    const int tid = threadIdx.x;
    const size_t nbase = (size_t)blockIdx.x * BM;

    // fused bucket count: this block's 1024-edge chunk, LDS hist in reused wt
    {
        int* hist = (int*)wt;
        for (int i = tid; i < NBUCK; i += 256) hist[i] = 0;
        __syncthreads();
        #pragma unroll
        for (int i = 0; i < CHUNK / 256; ++i) {
            const int e = blockIdx.x * CHUNK + tid + i * 256;
            if (e < NEDGES) atomicAdd(&hist[ei[NEDGES + e] >> 7], 1);
        }
        __syncthreads();
        for (int i = tid; i < NBUCK; i += 256)
            cnt[(size_t)blockIdx.x * NBUCK + i] = hist[i];
        __syncthreads();   // before wt staging overwrites hist
    }

    // stage wt rows 0..255 (linear copy of pre-swizzled bf16)
    {
        const fvec4* s = (const fvec4*)wt_g;
        fvec4* d = (fvec4*)wt;
        #pragma unroll
        for (int i = 0; i < 16; ++i) d[tid + 256 * i] = s[tid + 256 * i];
    }
    // stage xs: thread = (row r0, quarter kq); f32->bf16, swizzled store
    {
        const int r0 = tid >> 2;
        const int kq = (tid & 3) * 32;
        const bool valid = (nbase + r0) < NNODES;
        const float* xr = x + (nbase + r0) * INDIM + kq;
        #pragma unroll
        for (int j2 = 0; j2 < 4; ++j2) {
            usvec8 o;
            if (valid) {
                fvec4 p0 = *(const fvec4*)(xr + j2 * 8);
                fvec4 p1 = *(const fvec4*)(xr + j2 * 8 + 4);
                #pragma unroll
                for (int j = 0; j < 4; ++j) { o[j] = f2bf_rne(p0[j]); o[4 + j] = f2bf_rne(p1[j]); }
            } else {
                #pragma unroll
                for (int j = 0; j < 8; ++j) o[j] = 0;
            }
            const int slot = (kq >> 3) + j2;            // 0..15
            const int sw = slot ^ (r0 & 7);
            *(usvec8*)&xs[r0 * INDIM + sw * 8] = o;
        }
    }

    const int wid  = tid >> 6;
    const int lane = tid & 63;
    const int r = lane & 15;
    const int g = lane >> 4;
    const int arow = wid * 16 + r;

    // alpha-tile B fragments straight from global (L2-hot 4KB)
    bf8 wa[4];
    #pragma unroll
    for (int kk = 0; kk < 4; ++kk)
        wa[kk] = *(const bf8*)&wt_g[(size_t)(256 + r) * INDIM + kk * 32 + g * 8];

    __syncthreads();

    // A fragments (reused across all 17 col-tiles)
    bf8 a[4];
    #pragma unroll
    for (int kk = 0; kk < 4; ++kk) {
        const int sw = (kk * 4 + g) ^ (arow & 7);
        a[kk] = *(const bf8*)&xs[arow * INDIM + sw * 8];
    }

    f32x4 acc[17];
    #pragma unroll
    for (int t = 0; t < 17; ++t) acc[t] = (f32x4){0.f, 0.f, 0.f, 0.f};

    #pragma unroll
    for (int kk = 0; kk < 4; ++kk) {
        #pragma unroll
        for (int t = 0; t < 16; ++t) {
            const int n = t * 16 + r;
            const int sw = (kk * 4 + g) ^ (n & 7);
            const bf8 b = *(const bf8*)&wt[n * INDIM + sw * 8];
            acc[t] = __builtin_amdgcn_mfma_f32_16x16x32_bf16(a[kk], b, acc[t], 0, 0, 0);
        }
        acc[16] = __builtin_amdgcn_mfma_f32_16x16x32_bf16(a[kk], wa[kk], acc[16], 0, 0, 0);
    }

    // alphas: D[row=4g+ri][col=r]; r<8 -> alpha_l head r, r>=8 -> alpha_r
    #pragma unroll
    for (int ri = 0; ri < 4; ++ri) {
        const size_t node = nbase + wid * 16 + 4 * g + ri;
        if (node < NNODES) {
            if (r < 8) alpha_l[node * NH + r]       = acc[16][ri];
            else       alpha_r[node * NH + (r - 8)] = acc[16][ri];
        }
    }

    // epilogue: stage D into reused wt LDS (per-wave 8KB), then wide stores
    __syncthreads();   // all waves done reading wt
    unsigned short* st = wt + wid * 4096;   // 16 rows x 256 shorts
    #pragma unroll
    for (int t = 0; t < 16; ++t) {
        #pragma unroll
        for (int ri = 0; ri < 4; ++ri) {
            const int row = 4 * g + ri;
            st[row * 256 + ((t ^ (row & 7)) << 4) + r] = f2bf_rne(acc[t][ri]);
        }
    }
    __syncthreads();   // order LDS writes before cross-lane reads

    {
        const int li = lane & 15;
        const int t  = li >> 1;
        const int half = li & 1;
        #pragma unroll
        for (int it = 0; it < 4; ++it) {
            const int row = it * 4 + (lane >> 4);
            const size_t node = nbase + wid * 16 + row;
            const usvec8 vh = *(const usvec8*)&st[row * 256 + ((t ^ (row & 7)) << 4) + half * 8];
            const usvec8 vr = *(const usvec8*)&st[row * 256 + (((8 + t) ^ (row & 7)) << 4) + half * 8];
            if (node < NNODES) {
                *(usvec8*)&h16[node * HC + li * 8]     = vh;
                *(usvec8*)&resid16[node * HC + li * 8] = vr;
            }
        }
    }
}

// ---------------------------------------------------------------------------
// k_colscan: per bucket-column exclusive scan over the CBLK chunk counts
// (2 elems/thread, 1024 threads). cnt[blk][b] becomes the RELATIVE offset of
// chunk blk within bucket b; btot[b] = bucket edge count.
// ---------------------------------------------------------------------------
__global__ __launch_bounds__(1024) void k_colscan(int* __restrict__ cnt,
                                                  int* __restrict__ btot)
{
    __shared__ int sh[1024];
    const int b = blockIdx.x;
    const int t = threadIdx.x;
    const int i0 = 2 * t, i1 = 2 * t + 1;
    const int v0 = (i0 < CBLK) ? cnt[(size_t)i0 * NBUCK + b] : 0;
    const int v1 = (i1 < CBLK) ? cnt[(size_t)i1 * NBUCK + b] : 0;
    const int s = v0 + v1;
    sh[t] = s;
    __syncthreads();
    #pragma unroll
    for (int off = 1; off < 1024; off <<= 1) {
        int u = (t >= off) ? sh[t - off] : 0;
        __syncthreads();
        sh[t] += u;
        __syncthreads();
    }
    const int base = sh[t] - s;   // exclusive
    if (i0 < CBLK) cnt[(size_t)i0 * NBUCK + b] = base;
    if (i1 < CBLK) cnt[(size_t)i1 * NBUCK + b] = base + v0;
    if (t == 1023) btot[b] = sh[1023];
}

// ---------------------------------------------------------------------------
// k_bscan: exclusive scan of the 782 bucket totals -> bucket_base[0..NBUCK].
// ---------------------------------------------------------------------------
__global__ __launch_bounds__(1024) void k_bscan(const int* __restrict__ btot,
                                                int* __restrict__ bucket_base)
{
    __shared__ int sh[1024];
    const int t = threadIdx.x;
    const int v = (t < NBUCK) ? btot[t] : 0;
    sh[t] = v;
    __syncthreads();
    #pragma unroll
    for (int off = 1; off < 1024; off <<= 1) {
        int u = (t >= off) ? sh[t - off] : 0;
        __syncthreads();
        sh[t] += u;
        __syncthreads();
    }
    if (t < NBUCK) bucket_base[t] = sh[t] - v;
    if (t == 1023) bucket_base[NBUCK] = sh[1023];   // = NEDGES
}

// ---------------------------------------------------------------------------
// k_scat1b: place edges into bucket-partitioned `pairs` at precomputed
// (chunk,bucket) offsets; LDS cursors only. Payload: src(17b) | dst_local(7b).
// ---------------------------------------------------------------------------
__global__ __launch_bounds__(256) void k_scat1b(const int* __restrict__ ei,
                                                const int* __restrict__ cnt,
                                                const int* __restrict__ bucket_base,
                                                uint32_t* __restrict__ pairs)
{
    __shared__ int baseabs[NBUCK];
    __shared__ int cur[NBUCK];
    const int t = threadIdx.x;
    for (int i = t; i < NBUCK; i += 256) {
        baseabs[i] = cnt[(size_t)blockIdx.x * NBUCK + i] + bucket_base[i];
        cur[i] = 0;
    }
    __syncthreads();
    #pragma unroll
    for (int i = 0; i < CHUNK / 256; ++i) {
        const int e = blockIdx.x * CHUNK + t + i * 256;
        if (e < NEDGES) {
            const int src = ei[e];
            const int dst = ei[NEDGES + e];
            const int b = dst >> 7;
            const int pos = baseabs[b] + atomicAdd(&cur[b], 1);
            pairs[pos] = (uint32_t)src | ((uint32_t)(dst & 127) << 17);
        }
    }
}

// ---------------------------------------------------------------------------
// k_msg2: one block per 128-node bucket. LDS: acc[128][128] f32 (even/odd
// channel-interleaved to kill bank conflicts), ssum[128][8], ar[128][8].
// Stream the bucket's contiguous edge list; per edge (wave-wide): lane c
// computes w for head c>>3, loads h dword {2c,2c+1} (one 256B coalesced
// instr/edge), two conflict-free LDS float atomics. Epilogue: normalize,
// ELU, + resid, coalesced out write. No global atomics, no CSR.
// ---------------------------------------------------------------------------
__global__ __launch_bounds__(256) void k_msg2(
    const uint32_t* __restrict__ pairs,
    const int* __restrict__ bucket_base,
    const float* __restrict__ alpha_l,
    const float* __restrict__ alpha_r,
    const unsigned short* __restrict__ h16,
    const unsigned short* __restrict__ resid16,
    float* __restrict__ out)
{
    __shared__ float acc[NPB_M * HC];    // 64 KB; channel ch at (ch>>1)+(ch&1)*64
    __shared__ float ssum[NPB_M * NH];   // 4 KB
    __shared__ float arl[NPB_M * NH];    // 4 KB
    const int b = blockIdx.x;
    const int t = threadIdx.x;

    for (int i = t; i < NPB_M * HC; i += 256) acc[i] = 0.f;
    for (int i = t; i < NPB_M * NH; i += 256) {
        ssum[i] = 0.f;
        const int gi = b * NPB_M * NH + i;
        arl[i] = (gi < NNODES * NH) ? alpha_r[gi] : 0.f;
    }
    __syncthreads();

    const int ebeg = bucket_base[b];
    const int eend = bucket_base[b + 1];
    const int wid  = t >> 6;
    const int lane = t & 63;
    const int hd   = lane >> 3;          // head of channels {2*lane, 2*lane+1}

    for (int tile = ebeg + wid * 64; tile < eend; tile += 256) {
        const int nval = min(64, eend - tile);
        uint32_t code = 0;
        if (lane < nval) code = pairs[tile + lane];
        for (int j = 0; j < nval; ++j) {
            const uint32_t cj = __shfl(code, j);
            const int src  = cj & 0x1FFFFu;
            const int dstl = cj >> 17;
            float a = alpha_l[(size_t)src * NH + hd] + arl[dstl * NH + hd];
            a = fmaxf(a, LEAKY * a);
            const float w = __expf(a);
            const uint32_t hv = *(const uint32_t*)&h16[(size_t)src * HC + 2 * lane];
            atomicAdd(&acc[dstl * HC + lane],      w * bf2f(hv & 0xFFFFu));
            atomicAdd(&acc[dstl * HC + 64 + lane], w * bf2f(hv >> 16));
            if ((lane & 7) == 0) atomicAdd(&ssum[dstl * NH + hd], w);
        }
    }
    __syncthreads();

    const int nmax = min(NPB_M, NNODES - b * NPB_M);
    for (int i = t; i < nmax * NH; i += 256) ssum[i] = 1.f / (ssum[i] + SM_EPS);
    __syncthreads();

    for (int i = t; i < nmax * 32; i += 256) {    // 32 fvec4 per node
        const int nl = i >> 5;
        const int q  = i & 31;                     // channels 4q..4q+3
        const size_t node = (size_t)b * NPB_M + nl;
        const uint32_t* rp = (const uint32_t*)&resid16[node * HC + 4 * q];
        const uint32_t r0 = rp[0], r1 = rp[1];
        fvec4 v;
        #pragma unroll
        for (int j = 0; j < 4; ++j) {
            const int c = 4 * q + j;
            const float u = acc[nl * HC + (c >> 1) + (c & 1) * 64] * ssum[nl * NH + (c >> 4)];
            v[j] = (u > 0.f ? u : expm1f(u));
        }
        v[0] += bf2f(r0 & 0xFFFFu); v[1] += bf2f(r0 >> 16);
        v[2] += bf2f(r1 & 0xFFFFu); v[3] += bf2f(r1 >> 16);
        *(fvec4*)&out[node * HC + 4 * q] = v;
    }
}

extern "C" void kernel_launch(void* const* d_in, const int* in_sizes, int n_in,
                              void* d_out, int out_size, void* d_ws, size_t ws_size,
                              hipStream_t stream)
{
    const float* x     = (const float*)d_in[0];
    const int*   ei    = (const int*)d_in[1];
    const float* W_lin = (const float*)d_in[2];
    const float* att_l = (const float*)d_in[3];
    const float* att_r = (const float*)d_in[4];
    const float* W_res = (const float*)d_in[5];
    float* out = (float*)d_out;

    // workspace layout
    unsigned short* wt_g    = (unsigned short*)d_ws;              // 272*128
    unsigned short* h16     = wt_g + (size_t)WROWS * INDIM;       // N*128
    unsigned short* resid16 = h16 + (size_t)NNODES * HC;          // N*128
    float* alpha_l  = (float*)(resid16 + (size_t)NNODES * HC);    // N*8
    float* alpha_r  = alpha_l + (size_t)NNODES * NH;              // N*8
    int*   cnt      = (int*)(alpha_r + (size_t)NNODES * NH);      // CBLK*NBUCK
    int*   btot     = cnt + (size_t)CBLK * NBUCK;                 // NBUCK
    int*   bucket_base = btot + NBUCK;                            // NBUCK+1
    uint32_t* pairs = (uint32_t*)(bucket_base + NBUCK + 1);       // E

    k_wt<<<17, 256, 0, stream>>>(W_lin, W_res, att_l, att_r, wt_g);
    k_gemm<<<GEMM_BLOCKS, 256, 0, stream>>>(x, wt_g, ei, h16, resid16,
                                            alpha_l, alpha_r, cnt);
    k_colscan<<<NBUCK, 1024, 0, stream>>>(cnt, btot);
    k_bscan<<<1, 1024, 0, stream>>>(btot, bucket_base);
    k_scat1b<<<CBLK, 256, 0, stream>>>(ei, cnt, bucket_base, pairs);
    k_msg2<<<NBUCK, 256, 0, stream>>>(pairs, bucket_base, alpha_l, alpha_r,
                                      h16, resid16, out);
}

// Round 12
// 234.134 us; speedup vs baseline: 6.7376x; 6.7376x over previous
//
#include <hip/hip_runtime.h>
#include <cstdint>
#include <cstddef>

typedef __attribute__((ext_vector_type(4))) float fvec4;
typedef __attribute__((ext_vector_type(8))) short bf8;            // 8 bf16 = 4 VGPR MFMA frag
typedef __attribute__((ext_vector_type(8))) unsigned short usvec8;
typedef __attribute__((ext_vector_type(4))) unsigned int uvec4;
typedef __attribute__((ext_vector_type(4))) float f32x4;

#define NNODES 100000
#define NEDGES 1600000
#define INDIM  128
#define HC     128
#define NH     8
#define LEAKY  0.2f
#define SM_EPS 1e-16f
#define NPART  98    // ceil(100000/1024) for row_start scan
#define BM     64    // nodes per block in k_gemm
#define GEMM_BLOCKS ((NNODES + BM - 1) / BM)   // 1563
#define WROWS  272   // 256 W cols + 8 wa_l + 8 wa_r
#define NBUCK  196   // scatter buckets (512 nodes each; dst>>9)
#define NPB_S  512   // nodes per scatter bucket
#define CHUNK  1024  // edges per gemm block (fused count) / scat1b block
#define CBLK   GEMM_BLOCKS                     // 1563; 1563*1024 >= 1.6M

__device__ __forceinline__ unsigned short f2bf_rne(float f) {
    uint32_t u = __builtin_bit_cast(uint32_t, f);
    u += 0x7FFFu + ((u >> 16) & 1u);
    return (unsigned short)(u >> 16);
}
__device__ __forceinline__ float bf2f(uint32_t lo16) {
    return __builtin_bit_cast(float, lo16 << 16);
}

// ---------------------------------------------------------------------------
// k_wt: build wt_g (bf16):
//   rows 0..255:  W_lin|W_res transposed [n][k], pre-swizzled 16B slots (^= n&7)
//   rows 256..263: wa_l[k,hd]; rows 264..271: wa_r (att folded into W_lin).
// ---------------------------------------------------------------------------
__global__ __launch_bounds__(256) void k_wt(
    const float* __restrict__ W_lin,
    const float* __restrict__ W_res,
    const float* __restrict__ att_l,
    const float* __restrict__ att_r,
    unsigned short* __restrict__ wt_g)
{
    const int idx = blockIdx.x * 256 + threadIdx.x;   // 0..4351
    if (idx >= WROWS * 16) return;
    const int n  = idx >> 4;                          // 0..271
    const int k8 = idx & 15;
    usvec8 o;
    if (n < 256) {
        const float* src = (n < 128) ? W_lin : W_res;
        const int col = n & 127;
        #pragma unroll
        for (int j = 0; j < 8; ++j)
            o[j] = f2bf_rne(src[(size_t)(k8 * 8 + j) * HC + col]);
        const int sw = k8 ^ (n & 7);
        *(usvec8*)&wt_g[(size_t)n * INDIM + sw * 8] = o;
    } else {
        const int hd = (n - 256) & 7;
        const float* att = (n < 264) ? att_l : att_r;
        #pragma unroll
        for (int j = 0; j < 8; ++j) {
            const int k = k8 * 8 + j;
            float s = 0.f;
            #pragma unroll
            for (int c = 0; c < 16; ++c)
                s += W_lin[(size_t)k * HC + 16 * hd + c] * att[16 * hd + c];
            o[j] = f2bf_rne(s);
        }
        *(usvec8*)&wt_g[(size_t)n * INDIM + k8 * 8] = o;
    }
}

// ---------------------------------------------------------------------------
// k_gemm (MFMA): per block 64 nodes x 272 cols (h | resid | alphas), K=128.
// LDS: wt 64KB + xs 16KB = 80KB -> 2 blocks/CU.
// Fused: dst-degree histogram (global atomics, 16/address) AND per-(chunk,
// bucket) counts via LDS hist in reused wt (validated pattern, r11).
// ---------------------------------------------------------------------------
__global__ __launch_bounds__(256) void k_gemm(
    const float* __restrict__ x,
    const unsigned short* __restrict__ wt_g,
    const int*   __restrict__ ei,
    unsigned short* __restrict__ h16,
    unsigned short* __restrict__ resid16,
    float* __restrict__ alpha_l,
    float* __restrict__ alpha_r,
    int* __restrict__ deg,
    int* __restrict__ cnt)
{
    __shared__ unsigned short wt[256 * INDIM];  // 64 KB
    __shared__ unsigned short xs[BM * INDIM];   // 16 KB

    const int tid = threadIdx.x;
    const size_t nbase = (size_t)blockIdx.x * BM;

    // fused per-(chunk,bucket) count: this block's 1024-edge chunk, LDS hist
    // in reused wt; also global deg histogram (for row_start).
    {
        int* hist = (int*)wt;
        if (tid < NBUCK) hist[tid] = 0;
        __syncthreads();
        #pragma unroll
        for (int i = 0; i < CHUNK / 256; ++i) {
            const int e = blockIdx.x * CHUNK + tid + i * 256;
            if (e < NEDGES) {
                const int dst = ei[NEDGES + e];
                atomicAdd(&hist[dst >> 9], 1);
                atomicAdd(&deg[dst], 1);
            }
        }
        __syncthreads();
        if (tid < NBUCK) cnt[(size_t)blockIdx.x * NBUCK + tid] = hist[tid];
        __syncthreads();   // before wt staging overwrites hist
    }

    // stage wt rows 0..255 (linear copy of pre-swizzled bf16)
    {
        const fvec4* s = (const fvec4*)wt_g;
        fvec4* d = (fvec4*)wt;
        #pragma unroll
        for (int i = 0; i < 16; ++i) d[tid + 256 * i] = s[tid + 256 * i];
    }
    // stage xs: thread = (row r0, quarter kq); f32->bf16, swizzled store
    {
        const int r0 = tid >> 2;
        const int kq = (tid & 3) * 32;
        const bool valid = (nbase + r0) < NNODES;
        const float* xr = x + (nbase + r0) * INDIM + kq;
        #pragma unroll
        for (int j2 = 0; j2 < 4; ++j2) {
            usvec8 o;
            if (valid) {
                fvec4 p0 = *(const fvec4*)(xr + j2 * 8);
                fvec4 p1 = *(const fvec4*)(xr + j2 * 8 + 4);
                #pragma unroll
                for (int j = 0; j < 4; ++j) { o[j] = f2bf_rne(p0[j]); o[4 + j] = f2bf_rne(p1[j]); }
            } else {
                #pragma unroll
                for (int j = 0; j < 8; ++j) o[j] = 0;
            }
            const int slot = (kq >> 3) + j2;            // 0..15
            const int sw = slot ^ (r0 & 7);
            *(usvec8*)&xs[r0 * INDIM + sw * 8] = o;
        }
    }

    const int wid  = tid >> 6;
    const int lane = tid & 63;
    const int r = lane & 15;
    const int g = lane >> 4;
    const int arow = wid * 16 + r;

    // alpha-tile B fragments straight from global (L2-hot 4KB)
    bf8 wa[4];
    #pragma unroll
    for (int kk = 0; kk < 4; ++kk)
        wa[kk] = *(const bf8*)&wt_g[(size_t)(256 + r) * INDIM + kk * 32 + g * 8];

    __syncthreads();

    // A fragments (reused across all 17 col-tiles)
    bf8 a[4];
    #pragma unroll
    for (int kk = 0; kk < 4; ++kk) {
        const int sw = (kk * 4 + g) ^ (arow & 7);
        a[kk] = *(const bf8*)&xs[arow * INDIM + sw * 8];
    }

    f32x4 acc[17];
    #pragma unroll
    for (int t = 0; t < 17; ++t) acc[t] = (f32x4){0.f, 0.f, 0.f, 0.f};

    #pragma unroll
    for (int kk = 0; kk < 4; ++kk) {
        #pragma unroll
        for (int t = 0; t < 16; ++t) {
            const int n = t * 16 + r;
            const int sw = (kk * 4 + g) ^ (n & 7);
            const bf8 b = *(const bf8*)&wt[n * INDIM + sw * 8];
            acc[t] = __builtin_amdgcn_mfma_f32_16x16x32_bf16(a[kk], b, acc[t], 0, 0, 0);
        }
        acc[16] = __builtin_amdgcn_mfma_f32_16x16x32_bf16(a[kk], wa[kk], acc[16], 0, 0, 0);
    }

    // alphas: D[row=4g+ri][col=r]; r<8 -> alpha_l head r, r>=8 -> alpha_r
    #pragma unroll
    for (int ri = 0; ri < 4; ++ri) {
        const size_t node = nbase + wid * 16 + 4 * g + ri;
        if (node < NNODES) {
            if (r < 8) alpha_l[node * NH + r]       = acc[16][ri];
            else       alpha_r[node * NH + (r - 8)] = acc[16][ri];
        }
    }

    // epilogue: stage D into reused wt LDS (per-wave 8KB), then wide stores
    __syncthreads();   // all waves done reading wt
    unsigned short* st = wt + wid * 4096;   // 16 rows x 256 shorts
    #pragma unroll
    for (int t = 0; t < 16; ++t) {
        #pragma unroll
        for (int ri = 0; ri < 4; ++ri) {
            const int row = 4 * g + ri;
            st[row * 256 + ((t ^ (row & 7)) << 4) + r] = f2bf_rne(acc[t][ri]);
        }
    }
    __syncthreads();   // order LDS writes before cross-lane reads

    {
        const int li = lane & 15;
        const int t  = li >> 1;
        const int half = li & 1;
        #pragma unroll
        for (int it = 0; it < 4; ++it) {
            const int row = it * 4 + (lane >> 4);
            const size_t node = nbase + wid * 16 + row;
            const usvec8 vh = *(const usvec8*)&st[row * 256 + ((t ^ (row & 7)) << 4) + half * 8];
            const usvec8 vr = *(const usvec8*)&st[row * 256 + (((8 + t) ^ (row & 7)) << 4) + half * 8];
            if (node < NNODES) {
                *(usvec8*)&h16[node * HC + li * 8]     = vh;
                *(usvec8*)&resid16[node * HC + li * 8] = vr;
            }
        }
    }
}

// ---------------------------------------------------------------------------
// CSR row_start: two-level scan over deg
// ---------------------------------------------------------------------------
__global__ __launch_bounds__(1024) void k_scan1(const int* __restrict__ deg,
                                                int* __restrict__ row_start,
                                                int* __restrict__ partials)
{
    __shared__ int sh[1024];
    const int t = threadIdx.x;
    const int i = blockIdx.x * 1024 + t;
    const int v = (i < NNODES) ? deg[i] : 0;
    sh[t] = v;
    __syncthreads();
    #pragma unroll
    for (int off = 1; off < 1024; off <<= 1) {
        int u = (t >= off) ? sh[t - off] : 0;
        __syncthreads();
        sh[t] += u;
        __syncthreads();
    }
    if (i < NNODES) row_start[i] = sh[t] - v;
    if (t == 1023) partials[blockIdx.x] = sh[1023];
}

__global__ __launch_bounds__(128) void k_scan2(int* __restrict__ partials)
{
    __shared__ int sh[128];
    const int t = threadIdx.x;
    const int v = (t < NPART) ? partials[t] : 0;
    sh[t] = v;
    __syncthreads();
    #pragma unroll
    for (int off = 1; off < 128; off <<= 1) {
        int u = (t >= off) ? sh[t - off] : 0;
        __syncthreads();
        sh[t] += u;
        __syncthreads();
    }
    if (t < NPART) partials[t] = sh[t] - v;
    if (t == 127) partials[NPART] = sh[127];
}

__global__ __launch_bounds__(1024) void k_scan3(int* __restrict__ row_start,
                                                const int* __restrict__ partials)
{
    const int i = blockIdx.x * 1024 + threadIdx.x;
    if (i < NNODES) row_start[i] += partials[blockIdx.x];
    if (i == NNODES - 1) row_start[NNODES] = partials[NPART];
}

// ---------------------------------------------------------------------------
// k_colscan: per bucket-column exclusive scan over CBLK chunk counts
// (2 elems/thread) + bucket CSR base -> absolute (chunk,bucket) offsets.
// ---------------------------------------------------------------------------
__global__ __launch_bounds__(1024) void k_colscan(int* __restrict__ cnt,
                                                  const int* __restrict__ row_start)
{
    __shared__ int sh[1024];
    const int b = blockIdx.x;
    const int t = threadIdx.x;
    const int i0 = 2 * t, i1 = 2 * t + 1;
    const int v0 = (i0 < CBLK) ? cnt[(size_t)i0 * NBUCK + b] : 0;
    const int v1 = (i1 < CBLK) ? cnt[(size_t)i1 * NBUCK + b] : 0;
    const int s = v0 + v1;
    sh[t] = s;
    __syncthreads();
    #pragma unroll
    for (int off = 1; off < 1024; off <<= 1) {
        int u = (t >= off) ? sh[t - off] : 0;
        __syncthreads();
        sh[t] += u;
        __syncthreads();
    }
    const int base = sh[t] - s + row_start[b * NPB_S];   // absolute exclusive
    if (i0 < CBLK) cnt[(size_t)i0 * NBUCK + b] = base;
    if (i1 < CBLK) cnt[(size_t)i1 * NBUCK + b] = base + v0;
}

// ---------------------------------------------------------------------------
// k_scat1b: place edges into bucket-partitioned `pairs` at precomputed
// (chunk,bucket) offsets; LDS cursors only. Payload: src(17b) | dst_local(9b).
// ---------------------------------------------------------------------------
__global__ __launch_bounds__(256) void k_scat1b(const int* __restrict__ ei,
                                                const int* __restrict__ ofs,
                                                uint32_t* __restrict__ pairs)
{
    __shared__ int base[NBUCK];
    __shared__ int cur[NBUCK];
    const int t = threadIdx.x;
    if (t < NBUCK) { base[t] = ofs[(size_t)blockIdx.x * NBUCK + t]; cur[t] = 0; }
    __syncthreads();
    #pragma unroll
    for (int i = 0; i < CHUNK / 256; ++i) {
        const int e = blockIdx.x * CHUNK + t + i * 256;
        if (e < NEDGES) {
            const int src = ei[e];
            const int dst = ei[NEDGES + e];
            const int b = dst >> 9;
            const int pos = base[b] + atomicAdd(&cur[b], 1);
            pairs[pos] = (uint32_t)src | ((uint32_t)(dst & 511) << 17);
        }
    }
}

// ---------------------------------------------------------------------------
// k_scat2: one block per bucket; LDS per-node cursors resolve exact CSR
// positions; all writes inside the bucket's ~33KB L2-resident window.
// ---------------------------------------------------------------------------
__global__ __launch_bounds__(1024) void k_scat2(const uint32_t* __restrict__ pairs,
                                                const int* __restrict__ row_start,
                                                int* __restrict__ csr_src)
{
    __shared__ int rs[NPB_S + 1];
    __shared__ int lc[NPB_S];
    const int base = blockIdx.x * NPB_S;
    const int nmax = min(NPB_S, NNODES - base);
    const int t = threadIdx.x;
    if (t <= nmax) rs[t] = row_start[base + t];
    if (t < nmax)  lc[t] = 0;
    __syncthreads();
    const int bs = rs[0];
    const int be = rs[nmax];
    for (int i = bs + t; i < be; i += 1024) {
        const uint32_t code = pairs[i];
        const int src  = code & 0x1FFFFu;
        const int dstl = code >> 17;
        const int pos = rs[dstl] + atomicAdd(&lc[dstl], 1);
        csr_src[pos] = src;
    }
}

// ---------------------------------------------------------------------------
// k_msg: one wave per dst node, 8 edges per iteration, shuffle-free score
// mapping (round-9 version, measured 103µs = gather-throughput ceiling).
// lane = (sub = lane>>3 -> edge slot, li = lane&7 -> 16-channel block ==
// head li). 3-level xor-reduce over sub; lanes sub==0 write 16 channels.
// ---------------------------------------------------------------------------
__global__ __launch_bounds__(256) void k_msg(
    const int* __restrict__ row_start,
    const int* __restrict__ csr_src,
    const float* __restrict__ alpha_l,
    const float* __restrict__ alpha_r,
    const unsigned short* __restrict__ h16,
    const unsigned short* __restrict__ resid16,
    float* __restrict__ out)
{
    const int n = blockIdx.x * 4 + (threadIdx.x >> 6);
    if (n >= NNODES) return;
    const int lane = threadIdx.x & 63;
    const int sub  = lane >> 3;     // edge slot 0..7
    const int li   = lane & 7;      // channel block / head 0..7

    const int beg = row_start[n];
    const int end = row_start[n + 1];
    const float ar = alpha_r[(size_t)n * NH + li];
    const float* __restrict__ al_li = alpha_l + li;
    const unsigned short* __restrict__ hbase = h16 + 16 * li;

    float ssum = 0.f;
    float acc[16];
    #pragma unroll
    for (int j = 0; j < 16; ++j) acc[j] = 0.f;

    for (int p = beg; p < end; p += 8) {
        const int q = p + sub;
        const bool valid = q < end;
        const int qc = valid ? q : beg;
        const int src = csr_src[qc];
        float a = al_li[(size_t)src * NH] + ar;
        a = a > 0.f ? a : LEAKY * a;
        const float w = valid ? __expf(a) : 0.f;
        ssum += w;
        const unsigned short* hrow = hbase + (size_t)src * HC;
        const uvec4 d0 = *(const uvec4*)hrow;
        const uvec4 d1 = *(const uvec4*)(hrow + 8);
        #pragma unroll
        for (int c = 0; c < 4; ++c) {
            acc[2 * c]         += w * __builtin_bit_cast(float, d0[c] << 16);
            acc[2 * c + 1]     += w * __builtin_bit_cast(float, d0[c] & 0xFFFF0000u);
            acc[8 + 2 * c]     += w * __builtin_bit_cast(float, d1[c] << 16);
            acc[8 + 2 * c + 1] += w * __builtin_bit_cast(float, d1[c] & 0xFFFF0000u);
        }
    }

    // reduce across the 8 edge subgroups (lane bits 3,4,5); li preserved
    ssum += __shfl_xor(ssum, 8);
    ssum += __shfl_xor(ssum, 16);
    ssum += __shfl_xor(ssum, 32);
    #pragma unroll
    for (int j = 0; j < 16; ++j) {
        acc[j] += __shfl_xor(acc[j], 8);
        acc[j] += __shfl_xor(acc[j], 16);
        acc[j] += __shfl_xor(acc[j], 32);
    }

    if (sub == 0) {
        const float inv = 1.f / (ssum + SM_EPS);
        const unsigned short* rrow = resid16 + (size_t)n * HC + 16 * li;
        const uvec4 r0 = *(const uvec4*)rrow;
        const uvec4 r1 = *(const uvec4*)(rrow + 8);
        float res[16];
        #pragma unroll
        for (int c = 0; c < 4; ++c) {
            res[2 * c]         = __builtin_bit_cast(float, r0[c] << 16);
            res[2 * c + 1]     = __builtin_bit_cast(float, r0[c] & 0xFFFF0000u);
            res[8 + 2 * c]     = __builtin_bit_cast(float, r1[c] << 16);
            res[8 + 2 * c + 1] = __builtin_bit_cast(float, r1[c] & 0xFFFF0000u);
        }
        float* orow = out + (size_t)n * HC + 16 * li;
        #pragma unroll
        for (int v4 = 0; v4 < 4; ++v4) {
            fvec4 o;
            #pragma unroll
            for (int j = 0; j < 4; ++j) {
                float v = acc[v4 * 4 + j] * inv;
                o[j] = (v > 0.f ? v : expm1f(v)) + res[v4 * 4 + j];
            }
            *(fvec4*)&orow[v4 * 4] = o;
        }
    }
}

extern "C" void kernel_launch(void* const* d_in, const int* in_sizes, int n_in,
                              void* d_out, int out_size, void* d_ws, size_t ws_size,
                              hipStream_t stream)
{
    const float* x     = (const float*)d_in[0];
    const int*   ei    = (const int*)d_in[1];
    const float* W_lin = (const float*)d_in[2];
    const float* att_l = (const float*)d_in[3];
    const float* att_r = (const float*)d_in[4];
    const float* W_res = (const float*)d_in[5];
    float* out = (float*)d_out;

    // workspace layout
    unsigned short* wt_g    = (unsigned short*)d_ws;              // 272*128
    unsigned short* h16     = wt_g + (size_t)WROWS * INDIM;       // N*128
    unsigned short* resid16 = h16 + (size_t)NNODES * HC;          // N*128
    float* alpha_l  = (float*)(resid16 + (size_t)NNODES * HC);    // N*8
    float* alpha_r  = alpha_l + (size_t)NNODES * NH;              // N*8
    int*   deg      = (int*)(alpha_r + (size_t)NNODES * NH);      // N
    int*   row_start= deg + NNODES;                               // N+1
    int*   partials = row_start + NNODES + 1;                     // NPART+1
    int*   cnt      = partials + NPART + 1;                       // CBLK*NBUCK
    uint32_t* pairs = (uint32_t*)(cnt + (size_t)CBLK * NBUCK);    // E
    int*   csr_src  = (int*)(pairs + NEDGES);                     // E

    // zero deg every launch (ws is not re-poisoned between replays)
    hipMemsetAsync(deg, 0, (size_t)NNODES * sizeof(int), stream);

    k_wt<<<17, 256, 0, stream>>>(W_lin, W_res, att_l, att_r, wt_g);
    k_gemm<<<GEMM_BLOCKS, 256, 0, stream>>>(x, wt_g, ei, h16, resid16,
                                            alpha_l, alpha_r, deg, cnt);
    k_scan1<<<NPART, 1024, 0, stream>>>(deg, row_start, partials);
    k_scan2<<<1, 128, 0, stream>>>(partials);
    k_scan3<<<NPART, 1024, 0, stream>>>(row_start, partials);
    k_colscan<<<NBUCK, 1024, 0, stream>>>(cnt, row_start);
    k_scat1b<<<CBLK, 256, 0, stream>>>(ei, cnt, pairs);
    k_scat2<<<NBUCK, 1024, 0, stream>>>(pairs, row_start, csr_src);
    k_msg<<<(NNODES + 3) / 4, 256, 0, stream>>>(row_start, csr_src, alpha_l, alpha_r,
                                                h16, resid16, out);
}

// Round 13
// 180.600 us; speedup vs baseline: 8.7347x; 1.2964x over previous
//
#include <hip/hip_runtime.h>
#include <cstdint>
#include <cstddef>

typedef __attribute__((ext_vector_type(4))) float fvec4;
typedef __attribute__((ext_vector_type(8))) short bf8;            // 8 bf16 = 4 VGPR MFMA frag
typedef __attribute__((ext_vector_type(8))) unsigned short usvec8;
typedef __attribute__((ext_vector_type(4))) unsigned int uvec4;
typedef __attribute__((ext_vector_type(4))) float f32x4;

#define NNODES 100000
#define NEDGES 1600000
#define INDIM  128
#define HC     128
#define NH     8
#define LEAKY  0.2f
#define SM_EPS 1e-16f
#define BM     64    // nodes per block in k_gemm
#define GEMM_BLOCKS ((NNODES + BM - 1) / BM)   // 1563
#define WROWS  272   // 256 W cols + 8 wa_l + 8 wa_r
#define NBUCK  196   // scatter buckets (512 nodes each; dst>>9)
#define NPB_S  512   // nodes per scatter bucket
#define CHUNK  1024  // edges per gemm block (fused count) / scat1b block
#define CBLK   GEMM_BLOCKS                     // 1563; 1563*1024 >= 1.6M

__device__ __forceinline__ unsigned short f2bf_rne(float f) {
    uint32_t u = __builtin_bit_cast(uint32_t, f);
    u += 0x7FFFu + ((u >> 16) & 1u);
    return (unsigned short)(u >> 16);
}
__device__ __forceinline__ float bf2f(uint32_t lo16) {
    return __builtin_bit_cast(float, lo16 << 16);
}

// ---------------------------------------------------------------------------
// k_wt: build wt_g (bf16):
//   rows 0..255:  W_lin|W_res transposed [n][k], pre-swizzled 16B slots (^= n&7)
//   rows 256..263: wa_l[k,hd]; rows 264..271: wa_r (att folded into W_lin).
// ---------------------------------------------------------------------------
__global__ __launch_bounds__(256) void k_wt(
    const float* __restrict__ W_lin,
    const float* __restrict__ W_res,
    const float* __restrict__ att_l,
    const float* __restrict__ att_r,
    unsigned short* __restrict__ wt_g)
{
    const int idx = blockIdx.x * 256 + threadIdx.x;   // 0..4351
    if (idx >= WROWS * 16) return;
    const int n  = idx >> 4;                          // 0..271
    const int k8 = idx & 15;
    usvec8 o;
    if (n < 256) {
        const float* src = (n < 128) ? W_lin : W_res;
        const int col = n & 127;
        #pragma unroll
        for (int j = 0; j < 8; ++j)
            o[j] = f2bf_rne(src[(size_t)(k8 * 8 + j) * HC + col]);
        const int sw = k8 ^ (n & 7);
        *(usvec8*)&wt_g[(size_t)n * INDIM + sw * 8] = o;
    } else {
        const int hd = (n - 256) & 7;
        const float* att = (n < 264) ? att_l : att_r;
        #pragma unroll
        for (int j = 0; j < 8; ++j) {
            const int k = k8 * 8 + j;
            float s = 0.f;
            #pragma unroll
            for (int c = 0; c < 16; ++c)
                s += W_lin[(size_t)k * HC + 16 * hd + c] * att[16 * hd + c];
            o[j] = f2bf_rne(s);
        }
        *(usvec8*)&wt_g[(size_t)n * INDIM + k8 * 8] = o;
    }
}

// ---------------------------------------------------------------------------
// k_gemm (MFMA): per block 64 nodes x 272 cols (h | resid | alphas), K=128.
// LDS: wt 64KB + xs 16KB = 80KB -> 2 blocks/CU.
// Fused per-(chunk,bucket) counts via LDS hist in reused wt (validated r11).
// No global deg histogram anymore (row_start derived in k_scat2b).
// ---------------------------------------------------------------------------
__global__ __launch_bounds__(256) void k_gemm(
    const float* __restrict__ x,
    const unsigned short* __restrict__ wt_g,
    const int*   __restrict__ ei,
    unsigned short* __restrict__ h16,
    unsigned short* __restrict__ resid16,
    float* __restrict__ alpha_l,
    float* __restrict__ alpha_r,
    int* __restrict__ cnt)
{
    __shared__ unsigned short wt[256 * INDIM];  // 64 KB
    __shared__ unsigned short xs[BM * INDIM];   // 16 KB

    const int tid = threadIdx.x;
    const size_t nbase = (size_t)blockIdx.x * BM;

    // fused per-(chunk,bucket) count: this block's 1024-edge chunk, LDS hist
    {
        int* hist = (int*)wt;
        if (tid < NBUCK) hist[tid] = 0;
        __syncthreads();
        #pragma unroll
        for (int i = 0; i < CHUNK / 256; ++i) {
            const int e = blockIdx.x * CHUNK + tid + i * 256;
            if (e < NEDGES) atomicAdd(&hist[ei[NEDGES + e] >> 9], 1);
        }
        __syncthreads();
        if (tid < NBUCK) cnt[(size_t)blockIdx.x * NBUCK + tid] = hist[tid];
        __syncthreads();   // before wt staging overwrites hist
    }

    // stage wt rows 0..255 (linear copy of pre-swizzled bf16)
    {
        const fvec4* s = (const fvec4*)wt_g;
        fvec4* d = (fvec4*)wt;
        #pragma unroll
        for (int i = 0; i < 16; ++i) d[tid + 256 * i] = s[tid + 256 * i];
    }
    // stage xs: thread = (row r0, quarter kq); f32->bf16, swizzled store
    {
        const int r0 = tid >> 2;
        const int kq = (tid & 3) * 32;
        const bool valid = (nbase + r0) < NNODES;
        const float* xr = x + (nbase + r0) * INDIM + kq;
        #pragma unroll
        for (int j2 = 0; j2 < 4; ++j2) {
            usvec8 o;
            if (valid) {
                fvec4 p0 = *(const fvec4*)(xr + j2 * 8);
                fvec4 p1 = *(const fvec4*)(xr + j2 * 8 + 4);
                #pragma unroll
                for (int j = 0; j < 4; ++j) { o[j] = f2bf_rne(p0[j]); o[4 + j] = f2bf_rne(p1[j]); }
            } else {
                #pragma unroll
                for (int j = 0; j < 8; ++j) o[j] = 0;
            }
            const int slot = (kq >> 3) + j2;            // 0..15
            const int sw = slot ^ (r0 & 7);
            *(usvec8*)&xs[r0 * INDIM + sw * 8] = o;
        }
    }

    const int wid  = tid >> 6;
    const int lane = tid & 63;
    const int r = lane & 15;
    const int g = lane >> 4;
    const int arow = wid * 16 + r;

    // alpha-tile B fragments straight from global (L2-hot 4KB)
    bf8 wa[4];
    #pragma unroll
    for (int kk = 0; kk < 4; ++kk)
        wa[kk] = *(const bf8*)&wt_g[(size_t)(256 + r) * INDIM + kk * 32 + g * 8];

    __syncthreads();

    // A fragments (reused across all 17 col-tiles)
    bf8 a[4];
    #pragma unroll
    for (int kk = 0; kk < 4; ++kk) {
        const int sw = (kk * 4 + g) ^ (arow & 7);
        a[kk] = *(const bf8*)&xs[arow * INDIM + sw * 8];
    }

    f32x4 acc[17];
    #pragma unroll
    for (int t = 0; t < 17; ++t) acc[t] = (f32x4){0.f, 0.f, 0.f, 0.f};

    #pragma unroll
    for (int kk = 0; kk < 4; ++kk) {
        #pragma unroll
        for (int t = 0; t < 16; ++t) {
            const int n = t * 16 + r;
            const int sw = (kk * 4 + g) ^ (n & 7);
            const bf8 b = *(const bf8*)&wt[n * INDIM + sw * 8];
            acc[t] = __builtin_amdgcn_mfma_f32_16x16x32_bf16(a[kk], b, acc[t], 0, 0, 0);
        }
        acc[16] = __builtin_amdgcn_mfma_f32_16x16x32_bf16(a[kk], wa[kk], acc[16], 0, 0, 0);
    }

    // alphas: D[row=4g+ri][col=r]; r<8 -> alpha_l head r, r>=8 -> alpha_r
    #pragma unroll
    for (int ri = 0; ri < 4; ++ri) {
        const size_t node = nbase + wid * 16 + 4 * g + ri;
        if (node < NNODES) {
            if (r < 8) alpha_l[node * NH + r]       = acc[16][ri];
            else       alpha_r[node * NH + (r - 8)] = acc[16][ri];
        }
    }

    // epilogue: stage D into reused wt LDS (per-wave 8KB), then wide stores
    __syncthreads();   // all waves done reading wt
    unsigned short* st = wt + wid * 4096;   // 16 rows x 256 shorts
    #pragma unroll
    for (int t = 0; t < 16; ++t) {
        #pragma unroll
        for (int ri = 0; ri < 4; ++ri) {
            const int row = 4 * g + ri;
            st[row * 256 + ((t ^ (row & 7)) << 4) + r] = f2bf_rne(acc[t][ri]);
        }
    }
    __syncthreads();   // order LDS writes before cross-lane reads

    {
        const int li = lane & 15;
        const int t  = li >> 1;
        const int half = li & 1;
        #pragma unroll
        for (int it = 0; it < 4; ++it) {
            const int row = it * 4 + (lane >> 4);
            const size_t node = nbase + wid * 16 + row;
            const usvec8 vh = *(const usvec8*)&st[row * 256 + ((t ^ (row & 7)) << 4) + half * 8];
            const usvec8 vr = *(const usvec8*)&st[row * 256 + (((8 + t) ^ (row & 7)) << 4) + half * 8];
            if (node < NNODES) {
                *(usvec8*)&h16[node * HC + li * 8]     = vh;
                *(usvec8*)&resid16[node * HC + li * 8] = vr;
            }
        }
    }
}

// ---------------------------------------------------------------------------
// k_colscan: per bucket-column exclusive scan over CBLK chunk counts
// (2 elems/thread) -> relative (chunk,bucket) offsets; btot[b] = bucket total.
// (validated r11)
// ---------------------------------------------------------------------------
__global__ __launch_bounds__(1024) void k_colscan(int* __restrict__ cnt,
                                                  int* __restrict__ btot)
{
    __shared__ int sh[1024];
    const int b = blockIdx.x;
    const int t = threadIdx.x;
    const int i0 = 2 * t, i1 = 2 * t + 1;
    const int v0 = (i0 < CBLK) ? cnt[(size_t)i0 * NBUCK + b] : 0;
    const int v1 = (i1 < CBLK) ? cnt[(size_t)i1 * NBUCK + b] : 0;
    const int s = v0 + v1;
    sh[t] = s;
    __syncthreads();
    #pragma unroll
    for (int off = 1; off < 1024; off <<= 1) {
        int u = (t >= off) ? sh[t - off] : 0;
        __syncthreads();
        sh[t] += u;
        __syncthreads();
    }
    const int base = sh[t] - s;   // exclusive
    if (i0 < CBLK) cnt[(size_t)i0 * NBUCK + b] = base;
    if (i1 < CBLK) cnt[(size_t)i1 * NBUCK + b] = base + v0;
    if (t == 1023) btot[b] = sh[1023];
}

// ---------------------------------------------------------------------------
// k_bscan: exclusive scan of bucket totals -> bucket_base[0..NBUCK].
// (validated r11)
// ---------------------------------------------------------------------------
__global__ __launch_bounds__(1024) void k_bscan(const int* __restrict__ btot,
                                                int* __restrict__ bucket_base)
{
    __shared__ int sh[1024];
    const int t = threadIdx.x;
    const int v = (t < NBUCK) ? btot[t] : 0;
    sh[t] = v;
    __syncthreads();
    #pragma unroll
    for (int off = 1; off < 1024; off <<= 1) {
        int u = (t >= off) ? sh[t - off] : 0;
        __syncthreads();
        sh[t] += u;
        __syncthreads();
    }
    if (t < NBUCK) bucket_base[t] = sh[t] - v;
    if (t == 1023) bucket_base[NBUCK] = sh[1023];   // = NEDGES
}

// ---------------------------------------------------------------------------
// k_scat1b: place edges into bucket-partitioned `pairs` at precomputed
// (chunk,bucket) offsets + bucket_base; LDS cursors only.
// Payload: src(17b) | dst_local(9b). (validated r11)
// ---------------------------------------------------------------------------
__global__ __launch_bounds__(256) void k_scat1b(const int* __restrict__ ei,
                                                const int* __restrict__ cnt,
                                                const int* __restrict__ bucket_base,
                                                uint32_t* __restrict__ pairs)
{
    __shared__ int baseabs[NBUCK];
    __shared__ int cur[NBUCK];
    const int t = threadIdx.x;
    if (t < NBUCK) {
        baseabs[t] = cnt[(size_t)blockIdx.x * NBUCK + t] + bucket_base[t];
        cur[t] = 0;
    }
    __syncthreads();
    #pragma unroll
    for (int i = 0; i < CHUNK / 256; ++i) {
        const int e = blockIdx.x * CHUNK + t + i * 256;
        if (e < NEDGES) {
            const int src = ei[e];
            const int dst = ei[NEDGES + e];
            const int b = dst >> 9;
            const int pos = baseabs[b] + atomicAdd(&cur[b], 1);
            pairs[pos] = (uint32_t)src | ((uint32_t)(dst & 511) << 17);
        }
    }
}

// ---------------------------------------------------------------------------
// k_scat2b: one block per bucket. Phase A: LDS histogram of dst_local over
// the bucket's pairs. Phase B: 512-entry LDS scan -> per-node offsets; write
// row_start for the bucket's nodes. Phase C: place edges into csr_src at
// exact CSR positions (bucket window is L2-hot). Replaces deg/scan1/2/3+scat2.
// ---------------------------------------------------------------------------
__global__ __launch_bounds__(1024) void k_scat2b(const uint32_t* __restrict__ pairs,
                                                 const int* __restrict__ bucket_base,
                                                 int* __restrict__ csr_src,
                                                 int* __restrict__ row_start)
{
    __shared__ int hist[NPB_S];   // counts, then reused as cursors
    __shared__ int rs[NPB_S];     // exclusive offsets (bucket-relative)
    const int b = blockIdx.x;
    const int t = threadIdx.x;
    const int node_base = b * NPB_S;
    const int nmax = min(NPB_S, NNODES - node_base);

    if (t < NPB_S) hist[t] = 0;
    __syncthreads();

    const int ebeg = bucket_base[b];
    const int eend = bucket_base[b + 1];

    // Phase A: histogram dst_local
    for (int i = ebeg + t; i < eend; i += 1024)
        atomicAdd(&hist[pairs[i] >> 17], 1);
    __syncthreads();

    // Phase B: exclusive scan of hist[0..511] into rs (Hillis-Steele)
    if (t < NPB_S) rs[t] = hist[t];
    __syncthreads();
    #pragma unroll
    for (int off = 1; off < NPB_S; off <<= 1) {
        int u = (t < NPB_S && t >= off) ? rs[t - off] : 0;
        __syncthreads();
        if (t < NPB_S) rs[t] += u;
        __syncthreads();
    }
    if (t < NPB_S) rs[t] -= hist[t];     // exclusive
    if (t < NPB_S) hist[t] = 0;          // reuse as cursor
    if (t < nmax) row_start[node_base + t] = ebeg + rs[t];
    if (t == 0 && node_base + nmax == NNODES) row_start[NNODES] = eend;
    __syncthreads();

    // Phase C: place edges at exact CSR positions
    for (int i = ebeg + t; i < eend; i += 1024) {
        const uint32_t code = pairs[i];
        const int src  = code & 0x1FFFFu;
        const int dstl = code >> 17;
        const int pos = ebeg + rs[dstl] + atomicAdd(&hist[dstl], 1);
        csr_src[pos] = src;
    }
}

// ---------------------------------------------------------------------------
// k_msg: one wave per dst node, 8 edges per iteration, shuffle-free score
// mapping (measured 103µs = random-gather traffic ceiling).
// lane = (sub = lane>>3 -> edge slot, li = lane&7 -> 16-channel block ==
// head li). 3-level xor-reduce over sub; lanes sub==0 write 16 channels.
// ---------------------------------------------------------------------------
__global__ __launch_bounds__(256) void k_msg(
    const int* __restrict__ row_start,
    const int* __restrict__ csr_src,
    const float* __restrict__ alpha_l,
    const float* __restrict__ alpha_r,
    const unsigned short* __restrict__ h16,
    const unsigned short* __restrict__ resid16,
    float* __restrict__ out)
{
    const int n = blockIdx.x * 4 + (threadIdx.x >> 6);
    if (n >= NNODES) return;
    const int lane = threadIdx.x & 63;
    const int sub  = lane >> 3;     // edge slot 0..7
    const int li   = lane & 7;      // channel block / head 0..7

    const int beg = row_start[n];
    const int end = row_start[n + 1];
    const float ar = alpha_r[(size_t)n * NH + li];
    const float* __restrict__ al_li = alpha_l + li;
    const unsigned short* __restrict__ hbase = h16 + 16 * li;

    float ssum = 0.f;
    float acc[16];
    #pragma unroll
    for (int j = 0; j < 16; ++j) acc[j] = 0.f;

    for (int p = beg; p < end; p += 8) {
        const int q = p + sub;
        const bool valid = q < end;
        const int qc = valid ? q : beg;
        const int src = csr_src[qc];
        float a = al_li[(size_t)src * NH] + ar;
        a = a > 0.f ? a : LEAKY * a;
        const float w = valid ? __expf(a) : 0.f;
        ssum += w;
        const unsigned short* hrow = hbase + (size_t)src * HC;
        const uvec4 d0 = *(const uvec4*)hrow;
        const uvec4 d1 = *(const uvec4*)(hrow + 8);
        #pragma unroll
        for (int c = 0; c < 4; ++c) {
            acc[2 * c]         += w * __builtin_bit_cast(float, d0[c] << 16);
            acc[2 * c + 1]     += w * __builtin_bit_cast(float, d0[c] & 0xFFFF0000u);
            acc[8 + 2 * c]     += w * __builtin_bit_cast(float, d1[c] << 16);
            acc[8 + 2 * c + 1] += w * __builtin_bit_cast(float, d1[c] & 0xFFFF0000u);
        }
    }

    // reduce across the 8 edge subgroups (lane bits 3,4,5); li preserved
    ssum += __shfl_xor(ssum, 8);
    ssum += __shfl_xor(ssum, 16);
    ssum += __shfl_xor(ssum, 32);
    #pragma unroll
    for (int j = 0; j < 16; ++j) {
        acc[j] += __shfl_xor(acc[j], 8);
        acc[j] += __shfl_xor(acc[j], 16);
        acc[j] += __shfl_xor(acc[j], 32);
    }

    if (sub == 0) {
        const float inv = 1.f / (ssum + SM_EPS);
        const unsigned short* rrow = resid16 + (size_t)n * HC + 16 * li;
        const uvec4 r0 = *(const uvec4*)rrow;
        const uvec4 r1 = *(const uvec4*)(rrow + 8);
        float res[16];
        #pragma unroll
        for (int c = 0; c < 4; ++c) {
            res[2 * c]         = __builtin_bit_cast(float, r0[c] << 16);
            res[2 * c + 1]     = __builtin_bit_cast(float, r0[c] & 0xFFFF0000u);
            res[8 + 2 * c]     = __builtin_bit_cast(float, r1[c] << 16);
            res[8 + 2 * c + 1] = __builtin_bit_cast(float, r1[c] & 0xFFFF0000u);
        }
        float* orow = out + (size_t)n * HC + 16 * li;
        #pragma unroll
        for (int v4 = 0; v4 < 4; ++v4) {
            fvec4 o;
            #pragma unroll
            for (int j = 0; j < 4; ++j) {
                float v = acc[v4 * 4 + j] * inv;
                o[j] = (v > 0.f ? v : expm1f(v)) + res[v4 * 4 + j];
            }
            *(fvec4*)&orow[v4 * 4] = o;
        }
    }
}

extern "C" void kernel_launch(void* const* d_in, const int* in_sizes, int n_in,
                              void* d_out, int out_size, void* d_ws, size_t ws_size,
                              hipStream_t stream)
{
    const float* x     = (const float*)d_in[0];
    const int*   ei    = (const int*)d_in[1];
    const float* W_lin = (const float*)d_in[2];
    const float* att_l = (const float*)d_in[3];
    const float* att_r = (const float*)d_in[4];
    const float* W_res = (const float*)d_in[5];
    float* out = (float*)d_out;

    // workspace layout (every buffer fully rewritten each launch; no memset)
    unsigned short* wt_g    = (unsigned short*)d_ws;              // 272*128
    unsigned short* h16     = wt_g + (size_t)WROWS * INDIM;       // N*128
    unsigned short* resid16 = h16 + (size_t)NNODES * HC;          // N*128
    float* alpha_l  = (float*)(resid16 + (size_t)NNODES * HC);    // N*8
    float* alpha_r  = alpha_l + (size_t)NNODES * NH;              // N*8
    int*   cnt      = (int*)(alpha_r + (size_t)NNODES * NH);      // CBLK*NBUCK
    int*   btot     = cnt + (size_t)CBLK * NBUCK;                 // NBUCK
    int*   bucket_base = btot + NBUCK;                            // NBUCK+1
    int*   row_start   = bucket_base + NBUCK + 1;                 // N+1
    uint32_t* pairs = (uint32_t*)(row_start + NNODES + 1);        // E
    int*   csr_src  = (int*)(pairs + NEDGES);                     // E

    k_wt<<<17, 256, 0, stream>>>(W_lin, W_res, att_l, att_r, wt_g);
    k_gemm<<<GEMM_BLOCKS, 256, 0, stream>>>(x, wt_g, ei, h16, resid16,
                                            alpha_l, alpha_r, cnt);
    k_colscan<<<NBUCK, 1024, 0, stream>>>(cnt, btot);
    k_bscan<<<1, 1024, 0, stream>>>(btot, bucket_base);
    k_scat1b<<<CBLK, 256, 0, stream>>>(ei, cnt, bucket_base, pairs);
    k_scat2b<<<NBUCK, 1024, 0, stream>>>(pairs, bucket_base, csr_src, row_start);
    k_msg<<<(NNODES + 3) / 4, 256, 0, stream>>>(row_start, csr_src, alpha_l, alpha_r,
                                                h16, resid16, out);
}